// Round 2
// baseline (597.023 us; speedup 1.0000x reference)
//
#include <hip/hip_runtime.h>
#include <stdint.h>

typedef short short8 __attribute__((ext_vector_type(8)));
typedef float f32x4 __attribute__((ext_vector_type(4)));

#define D 128
#define LOG2E 1.44269504088896340736f

__device__ __forceinline__ unsigned short f2bf(float f) {
    union { float f; unsigned u; } v; v.f = f;
    unsigned u = v.u;
    unsigned r = (u + 0x7FFFu + ((u >> 16) & 1u)) >> 16;  // RNE
    return (unsigned short)r;
}

// pack two f32 -> one u32 of two bf16 (round-half-up via +0x8000, then v_perm)
__device__ __forceinline__ unsigned packbf(float x, float y) {
    unsigned ux = __float_as_uint(x) + 0x8000u;
    unsigned uy = __float_as_uint(y) + 0x8000u;
    return __builtin_amdgcn_perm(uy, ux, 0x07060302u);  // [x.b2,x.b3,y.b2,y.b3]
}

__device__ __forceinline__ float sigm2(float z) {       // sigmoid, z pre-scaled by log2e
    return __builtin_amdgcn_rcpf(1.f + __builtin_amdgcn_exp2f(-z));
}

// ---------------------------------------------------------------------------
// Kernel 1: pre-pack (Wu * log2e) as bf16 MFMA B-fragments.
// t = nt*256 + kk*64 + lane holds B[k][col], col = nt*16+(lane&15),
// k = kk*32+(lane>>4)*8+j  (B[k][col] = Wu[col][k], u = f @ Wu^T)
// ---------------------------------------------------------------------------
__global__ __launch_bounds__(256) void pack_wu(const float* __restrict__ Wu,
                                               short8* __restrict__ frag) {
    int tid = blockIdx.x * 256 + threadIdx.x;
    int nt = tid >> 8, kk = (tid >> 6) & 3, l = tid & 63;
    int col = nt * 16 + (l & 15);
    int kb  = kk * 32 + ((l >> 4) * 8);
    short8 o;
#pragma unroll
    for (int j = 0; j < 8; ++j) o[j] = (short)f2bf(Wu[col * D + kb + j] * LOG2E);
    frag[tid] = o;
}

// ---------------------------------------------------------------------------
// Kernel 2: per-graph gates, pre-scaled by log2e:
//   vIb[g][h] = (Wv[h,:]·xI[last_g,:] + bu[h]) * log2e   (same for vVb / xV)
// ---------------------------------------------------------------------------
__global__ __launch_bounds__(128) void gate_k(const float* __restrict__ xI,
                                              const float* __restrict__ xV,
                                              const float* __restrict__ Wv,
                                              const float* __restrict__ bu,
                                              const int* __restrict__ lastn,
                                              float* __restrict__ vIb,
                                              float* __restrict__ vVb) {
    __shared__ float xi[D], xv[D];
    int g = blockIdx.x, t = threadIdx.x;
    int r = lastn[g];
    xi[t] = xI[(size_t)r * D + t];
    xv[t] = xV[(size_t)r * D + t];
    __syncthreads();
    const float4* wr = (const float4*)(Wv + (size_t)t * D);
    const float4* a4 = (const float4*)xi;
    const float4* b4 = (const float4*)xv;
    float sI = 0.f, sV = 0.f;
#pragma unroll 8
    for (int i = 0; i < D / 4; ++i) {
        float4 w = wr[i], a = a4[i], b = b4[i];
        sI += w.x * a.x + w.y * a.y + w.z * a.z + w.w * a.w;
        sV += w.x * b.x + w.y * b.y + w.z * b.z + w.w * b.w;
    }
    float bias = bu[t];
    vIb[(size_t)g * D + t] = (sI + bias) * LOG2E;
    vVb[(size_t)g * D + t] = (sV + bias) * LOG2E;
}

// ---------------------------------------------------------------------------
// Kernel 3: fused main. 4 graphs per block, ONE WAVE PER GRAPH, online softmax
// entirely wave-local (no cross-wave combine). All e-values in log2 units.
// ---------------------------------------------------------------------------
__global__ __launch_bounds__(256, 4) void attn_main(
    const float* __restrict__ xI, const float* __restrict__ xV,
    const float* __restrict__ We, const int* __restrict__ lastn,
    const float* __restrict__ vIb, const float* __restrict__ vVb,
    const short8* __restrict__ fragG, float* __restrict__ out, int B) {
    __shared__ short8 bfrag[2048];       // 32 KB: Wu bf16 fragments

    int t = threadIdx.x, lane = t & 63, w = t >> 6;

    // stage Wu fragments (contiguous 16B/lane -> conflict-free b128)
    {
        const uint4* src = (const uint4*)fragG;
        uint4* dst = (uint4*)bfrag;
#pragma unroll
        for (int i = 0; i < 8; ++i) dst[i * 256 + t] = src[i * 256 + t];
    }
    __syncthreads();

    int g = blockIdx.x * 4 + w;
    if (g >= B) return;

    int s = (g == 0) ? 0 : (lastn[g - 1] + 1);
    int n = lastn[g] + 1 - s;                       // >= 1

    // per-lane epilogue constants: col = nt*16 + (lane&15)
    float WeR[8], vIR[8], vVR[8];
#pragma unroll
    for (int nt = 0; nt < 8; ++nt) {
        int col = nt * 16 + (lane & 15);
        WeR[nt] = We[col] * LOG2E;                  // e in log2 units
        vIR[nt] = vIb[(size_t)g * D + col];
        vVR[nt] = vVb[(size_t)g * D + col];
    }

    float mI = -__builtin_inff(), mV = -__builtin_inff();
    float lIs = 0.f, lVs = 0.f;
    float aI0 = 0.f, aI1 = 0.f, aV0 = 0.f, aV1 = 0.f;

    int ch = (n + 15) >> 4;
    int total = 2 * ch;

    for (int c = 0; c < total; ++c) {
        int half = (c >= ch) ? 1 : 0;
        const float* src = half ? xV : xI;
        int base = (c - half * ch) * 16;

        // ---- A fragments: row = lane&15, k = kk*32 + (lane>>4)*8 + j ----
        int arow = base + (lane & 15);
        if (arow > n - 1) arow = n - 1;             // clamp (masked later)
        const float* rp = src + (size_t)(s + arow) * D + ((lane >> 4) * 8);
        short8 af[4];
#pragma unroll
        for (int kk = 0; kk < 4; ++kk) {
            float4 f0 = *(const float4*)(rp + kk * 32);
            float4 f1 = *(const float4*)(rp + kk * 32 + 4);
            union { unsigned u[4]; short8 s8; } cv;
            cv.u[0] = packbf(f0.x, f0.y);
            cv.u[1] = packbf(f0.z, f0.w);
            cv.u[2] = packbf(f1.x, f1.y);
            cv.u[3] = packbf(f1.z, f1.w);
            af[kk] = cv.s8;
        }

        // ---- GEMM + gate epilogue; pI[q] = e (log2 units) partials ----
        float pI[4] = {0.f, 0.f, 0.f, 0.f}, pV[4] = {0.f, 0.f, 0.f, 0.f};
#pragma unroll
        for (int nt = 0; nt < 8; ++nt) {
            f32x4 dacc = {0.f, 0.f, 0.f, 0.f};
#pragma unroll
            for (int kk = 0; kk < 4; ++kk)
                dacc = __builtin_amdgcn_mfma_f32_16x16x32_bf16(
                    af[kk], bfrag[nt * 256 + kk * 64 + lane], dacc, 0, 0, 0);
#pragma unroll
            for (int q = 0; q < 4; ++q) {
                float u = dacc[q];
                pI[q] = fmaf(WeR[nt], sigm2(u + vIR[nt]), pI[q]);
                pV[q] = fmaf(WeR[nt], sigm2(u + vVR[nt]), pV[q]);
            }
        }
        // reduce across 16 lanes (cols) of each quarter; mask invalid rows
#pragma unroll
        for (int q = 0; q < 4; ++q) {
#pragma unroll
            for (int off = 1; off < 16; off <<= 1) {
                pI[q] += __shfl_xor(pI[q], off);
                pV[q] += __shfl_xor(pV[q], off);
            }
            int r = ((lane >> 4) * 4) + q;
            if (base + r >= n) { pI[q] = -__builtin_inff(); pV[q] = -__builtin_inff(); }
        }
        float cmI = fmaxf(fmaxf(pI[0], pI[1]), fmaxf(pI[2], pI[3]));
        float cmV = fmaxf(fmaxf(pV[0], pV[1]), fmaxf(pV[2], pV[3]));
        cmI = fmaxf(cmI, __shfl_xor(cmI, 16)); cmI = fmaxf(cmI, __shfl_xor(cmI, 32));
        cmV = fmaxf(cmV, __shfl_xor(cmV, 16)); cmV = fmaxf(cmV, __shfl_xor(cmV, 32));

        float mnI = fmaxf(mI, cmI), mnV = fmaxf(mV, cmV);
        float scI = __builtin_amdgcn_exp2f(mI - mnI);
        float scV = __builtin_amdgcn_exp2f(mV - mnV);
        lIs *= scI; lVs *= scV;
        aI0 *= scI; aI1 *= scI; aV0 *= scV; aV1 *= scV;

        // online accumulate: rows re-read (L1-resident, just loaded)
#pragma unroll
        for (int r = 0; r < 16; ++r) {
            float eIr = __shfl(pI[r & 3], (r >> 2) << 4);
            float eVr = __shfl(pV[r & 3], (r >> 2) << 4);
            float wI = __builtin_amdgcn_exp2f(eIr - mnI);  // 0 for masked rows
            float wV = __builtin_amdgcn_exp2f(eVr - mnV);
            int rr = base + r; if (rr > n - 1) rr = n - 1;
            const float* fp = src + (size_t)(s + rr) * D;
            float f0 = fp[lane], f1 = fp[64 + lane];
            lIs += wI; lVs += wV;
            aI0 = fmaf(wI, f0, aI0); aI1 = fmaf(wI, f1, aI1);
            aV0 = fmaf(wV, f0, aV0); aV1 = fmaf(wV, f1, aV1);
        }
        mI = mnI; mV = mnV;
    }

    float rlI = __builtin_amdgcn_rcpf(lIs);
    float rlV = __builtin_amdgcn_rcpf(lVs);
    size_t og = (size_t)g * D;
    out[og + lane]      = aI0 * rlI;
    out[og + 64 + lane] = aI1 * rlI;
    size_t ov = (size_t)B * D + og;
    out[ov + lane]      = aV0 * rlV;
    out[ov + 64 + lane] = aV1 * rlV;
}

// ---------------------------------------------------------------------------
extern "C" void kernel_launch(void* const* d_in, const int* in_sizes, int n_in,
                              void* d_out, int out_size, void* d_ws, size_t ws_size,
                              hipStream_t stream) {
    const float* xI    = (const float*)d_in[0];
    const float* xV    = (const float*)d_in[1];
    const float* Wu    = (const float*)d_in[2];
    const float* bu    = (const float*)d_in[3];
    const float* Wv    = (const float*)d_in[4];
    const float* We    = (const float*)d_in[5];
    // d_in[6] = seg_ids (unused: segments contiguous, last_nodes suffices)
    const int*   lastn = (const int*)d_in[7];
    const int B = in_sizes[7];               // 8192

    float*  vIb   = (float*)d_ws;
    float*  vVb   = vIb + (size_t)B * D;
    short8* fragW = (short8*)(vVb + (size_t)B * D);

    pack_wu<<<8, 256, 0, stream>>>(Wu, fragW);
    gate_k<<<B, 128, 0, stream>>>(xI, xV, Wv, bu, lastn, vIb, vVb);
    attn_main<<<(B + 3) / 4, 256, 0, stream>>>(xI, xV, We, lastn, vIb, vVb,
                                               fragW, (float*)d_out, B);
}

// Round 3
// 419.354 us; speedup vs baseline: 1.4237x; 1.4237x over previous
//
#include <hip/hip_runtime.h>
#include <stdint.h>

typedef short short8 __attribute__((ext_vector_type(8)));
typedef float f32x4 __attribute__((ext_vector_type(4)));

#define D 128
#define LOG2E 1.44269504088896340736f

__device__ __forceinline__ unsigned short f2bf(float f) {
    union { float f; unsigned u; } v; v.f = f;
    unsigned u = v.u;
    unsigned r = (u + 0x7FFFu + ((u >> 16) & 1u)) >> 16;  // RNE
    return (unsigned short)r;
}

// pack two f32 -> one u32 of two bf16 (round-half-up via +0x8000, then v_perm)
__device__ __forceinline__ unsigned packbf(float x, float y) {
    unsigned ux = __float_as_uint(x) + 0x8000u;
    unsigned uy = __float_as_uint(y) + 0x8000u;
    return __builtin_amdgcn_perm(uy, ux, 0x07060302u);
}

__device__ __forceinline__ float sigm2(float z) {   // sigmoid, z in log2 units
    return __builtin_amdgcn_rcpf(1.f + __builtin_amdgcn_exp2f(-z));
}

// ---------------------------------------------------------------------------
// Kernel 1: pre-pack (Wu * log2e) as bf16 MFMA B-fragments.
// t = nt*256 + kk*64 + lane holds B[k][col], col = nt*16+(lane&15),
// k = kk*32+(lane>>4)*8+j  (B[k][col] = Wu[col][k], u = f @ Wu^T)
// ---------------------------------------------------------------------------
__global__ __launch_bounds__(256) void pack_wu(const float* __restrict__ Wu,
                                               short8* __restrict__ frag) {
    int tid = blockIdx.x * 256 + threadIdx.x;
    int nt = tid >> 8, kk = (tid >> 6) & 3, l = tid & 63;
    int col = nt * 16 + (l & 15);
    int kb  = kk * 32 + ((l >> 4) * 8);
    short8 o;
#pragma unroll
    for (int j = 0; j < 8; ++j) o[j] = (short)f2bf(Wu[col * D + kb + j] * LOG2E);
    frag[tid] = o;
}

// ---------------------------------------------------------------------------
// Kernel 2: per-graph gates (log2e pre-scaled)
// ---------------------------------------------------------------------------
__global__ __launch_bounds__(128) void gate_k(const float* __restrict__ xI,
                                              const float* __restrict__ xV,
                                              const float* __restrict__ Wv,
                                              const float* __restrict__ bu,
                                              const int* __restrict__ lastn,
                                              float* __restrict__ vIb,
                                              float* __restrict__ vVb) {
    __shared__ float xi[D], xv[D];
    int g = blockIdx.x, t = threadIdx.x;
    int r = lastn[g];
    xi[t] = xI[(size_t)r * D + t];
    xv[t] = xV[(size_t)r * D + t];
    __syncthreads();
    const float4* wr = (const float4*)(Wv + (size_t)t * D);
    const float4* a4 = (const float4*)xi;
    const float4* b4 = (const float4*)xv;
    float sI = 0.f, sV = 0.f;
#pragma unroll 8
    for (int i = 0; i < D / 4; ++i) {
        float4 w = wr[i], a = a4[i], b = b4[i];
        sI += w.x * a.x + w.y * a.y + w.z * a.z + w.w * a.w;
        sV += w.x * b.x + w.y * b.y + w.z * b.z + w.w * b.w;
    }
    float bias = bu[t];
    vIb[(size_t)g * D + t] = (sI + bias) * LOG2E;
    vVb[(size_t)g * D + t] = (sV + bias) * LOG2E;
}

// ---------------------------------------------------------------------------
// Kernel 3: fused main. Block per graph, 4 waves striding chunks.
// Rows staged to LDS via coalesced loads (read HBM exactly once); fragments
// AND accumulate both read LDS (XOR-swizzled, bank-balanced). Software
// pipeline: next chunk's global loads issued before current chunk's compute.
// ---------------------------------------------------------------------------
__global__ __launch_bounds__(256, 2) void attn_main(
    const float* __restrict__ xI, const float* __restrict__ xV,
    const float* __restrict__ We, const int* __restrict__ lastn,
    const float* __restrict__ vIb, const float* __restrict__ vVb,
    const short8* __restrict__ fragG, float* __restrict__ out, int B) {
    __shared__ short8 bfrag[2048];          // 32 KB Wu fragments
    __shared__ float rbuf[4][16 * 128];     // 32 KB wave-private row chunks
    __shared__ float cmbA[2][4][128];       // 4 KB combine
    __shared__ float cmbM[2][4], cmbL[2][4];

    int t = threadIdx.x, lane = t & 63, w = t >> 6;
    int g = blockIdx.x;

    {   // stage Wu fragments (contiguous 16B/lane)
        const uint4* srcf = (const uint4*)fragG;
        uint4* dst = (uint4*)bfrag;
#pragma unroll
        for (int i = 0; i < 8; ++i) dst[i * 256 + t] = srcf[i * 256 + t];
    }

    int s = (g == 0) ? 0 : (lastn[g - 1] + 1);
    int n = lastn[g] + 1 - s;                     // >= 1

    float WeR[8], vIR[8], vVR[8];
#pragma unroll
    for (int nt = 0; nt < 8; ++nt) {
        int col = nt * 16 + (lane & 15);
        WeR[nt] = We[col] * LOG2E;
        vIR[nt] = vIb[(size_t)g * D + col];
        vVR[nt] = vVb[(size_t)g * D + col];
    }
    __syncthreads();

    float mI = -__builtin_inff(), mV = -__builtin_inff();
    float lIs = 0.f, lVs = 0.f;
    float aI0 = 0.f, aI1 = 0.f, aV0 = 0.f, aV1 = 0.f;

    int ch = (n + 15) >> 4;
    int total = 2 * ch;
    char* rb = (char*)&rbuf[w][0];

    float4 pre[8];
    auto issue = [&](int cc) {      // coalesced: lane i -> contiguous 16B unit
        int hf = (cc >= ch) ? 1 : 0;
        const float* sp = hf ? xV : xI;
        int bb = (cc - hf * ch) << 4;
#pragma unroll
        for (int i = 0; i < 8; ++i) {
            int u = (i << 6) + lane;
            int rr = bb + (u >> 5); if (rr > n - 1) rr = n - 1;
            pre[i] = *(const float4*)(sp + (size_t)(s + rr) * D + ((u & 31) << 2));
        }
    };

    int c = w;
    if (c < total) issue(c);
    for (; c < total; c += 4) {
        // write staged regs -> LDS (swizzled: byte ^= (row&7)<<4)
#pragma unroll
        for (int i = 0; i < 8; ++i) {
            int u = (i << 6) + lane;
            int row = u >> 5;
            int byte = (row << 9) + ((u & 31) << 4);
            *(float4*)(rb + (byte ^ ((row & 7) << 4))) = pre[i];
        }
        if (c + 4 < total) issue(c + 4);   // prefetch next chunk (hidden by compute)

        int hf = (c >= ch) ? 1 : 0;
        int base = (c - hf * ch) << 4;

        // ---- A fragments from LDS: row = lane&15, dims (lane>>4)*8 + kk*32 ----
        short8 af[4];
        int arow = lane & 15;
        int sw = (arow & 7) << 4;
#pragma unroll
        for (int kk = 0; kk < 4; ++kk) {
            int byte = (arow << 9) + ((lane >> 4) << 5) + (kk << 7);
            float4 f0 = *(const float4*)(rb + (byte ^ sw));
            float4 f1 = *(const float4*)(rb + ((byte + 16) ^ sw));
            union { unsigned u[4]; short8 s8; } cv;
            cv.u[0] = packbf(f0.x, f0.y);
            cv.u[1] = packbf(f0.z, f0.w);
            cv.u[2] = packbf(f1.x, f1.y);
            cv.u[3] = packbf(f1.z, f1.w);
            af[kk] = cv.s8;
        }

        // ---- GEMM + gate epilogue (e in log2 units) ----
        float pI[4] = {0.f, 0.f, 0.f, 0.f}, pV[4] = {0.f, 0.f, 0.f, 0.f};
#pragma unroll
        for (int nt = 0; nt < 8; ++nt) {
            f32x4 dacc = {0.f, 0.f, 0.f, 0.f};
#pragma unroll
            for (int kk = 0; kk < 4; ++kk)
                dacc = __builtin_amdgcn_mfma_f32_16x16x32_bf16(
                    af[kk], bfrag[nt * 256 + kk * 64 + lane], dacc, 0, 0, 0);
#pragma unroll
            for (int q = 0; q < 4; ++q) {
                float u = dacc[q];
                pI[q] = fmaf(WeR[nt], sigm2(u + vIR[nt]), pI[q]);
                pV[q] = fmaf(WeR[nt], sigm2(u + vVR[nt]), pV[q]);
            }
        }
        // reduce across 16 lanes (cols); mask invalid rows
#pragma unroll
        for (int q = 0; q < 4; ++q) {
#pragma unroll
            for (int off = 1; off < 16; off <<= 1) {
                pI[q] += __shfl_xor(pI[q], off);
                pV[q] += __shfl_xor(pV[q], off);
            }
            int r = ((lane >> 4) * 4) + q;
            if (base + r >= n) { pI[q] = -__builtin_inff(); pV[q] = -__builtin_inff(); }
        }
        float cmI = fmaxf(fmaxf(pI[0], pI[1]), fmaxf(pI[2], pI[3]));
        float cmV = fmaxf(fmaxf(pV[0], pV[1]), fmaxf(pV[2], pV[3]));
        cmI = fmaxf(cmI, __shfl_xor(cmI, 16)); cmI = fmaxf(cmI, __shfl_xor(cmI, 32));
        cmV = fmaxf(cmV, __shfl_xor(cmV, 16)); cmV = fmaxf(cmV, __shfl_xor(cmV, 32));

        float mnI = fmaxf(mI, cmI), mnV = fmaxf(mV, cmV);
        float scI = __builtin_amdgcn_exp2f(mI - mnI);
        float scV = __builtin_amdgcn_exp2f(mV - mnV);
        lIs *= scI; lVs *= scV;
        aI0 *= scI; aI1 *= scI; aV0 *= scV; aV1 *= scV;

        // exponentiate once per group (8 trans), THEN broadcast weights
        float wIq[4], wVq[4];
#pragma unroll
        for (int q = 0; q < 4; ++q) {
            wIq[q] = __builtin_amdgcn_exp2f(pI[q] - mnI);   // 0 for masked rows
            wVq[q] = __builtin_amdgcn_exp2f(pV[q] - mnV);
        }
        float sI = wIq[0] + wIq[1] + wIq[2] + wIq[3];
        float sV = wVq[0] + wVq[1] + wVq[2] + wVq[3];
        sI += __shfl_xor(sI, 16); sI += __shfl_xor(sI, 32);
        sV += __shfl_xor(sV, 16); sV += __shfl_xor(sV, 32);
        lIs += sI; lVs += sV;

        // weighted accumulate from LDS (row-uniform reads, conflict-free)
#pragma unroll
        for (int r = 0; r < 16; ++r) {
            float wI = __shfl(wIq[r & 3], (r >> 2) << 4);
            float wV = __shfl(wVq[r & 3], (r >> 2) << 4);
            int rsw = (r & 7) << 4;
            float f0 = *(const float*)(rb + ((((r << 9) + (lane << 2))) ^ rsw));
            float f1 = *(const float*)(rb + ((((r << 9) + 256 + (lane << 2))) ^ rsw));
            aI0 = fmaf(wI, f0, aI0); aI1 = fmaf(wI, f1, aI1);
            aV0 = fmaf(wV, f0, aV0); aV1 = fmaf(wV, f1, aV1);
        }
        mI = mnI; mV = mnV;
    }

    // ---- cross-wave flash combine ----
    cmbA[0][w][lane] = aI0; cmbA[0][w][lane + 64] = aI1;
    cmbA[1][w][lane] = aV0; cmbA[1][w][lane + 64] = aV1;
    if (lane == 0) {
        cmbM[0][w] = mI; cmbL[0][w] = lIs;
        cmbM[1][w] = mV; cmbL[1][w] = lVs;
    }
    __syncthreads();
    {
        int st = t >> 7, d = t & 127;
        float M = fmaxf(fmaxf(cmbM[st][0], cmbM[st][1]),
                        fmaxf(cmbM[st][2], cmbM[st][3]));
        float Ls = 0.f, A = 0.f;
#pragma unroll
        for (int ww = 0; ww < 4; ++ww) {
            float e = __builtin_amdgcn_exp2f(cmbM[st][ww] - M);  // 0 for idle waves
            Ls += cmbL[st][ww] * e;
            A  += cmbA[st][ww][d] * e;
        }
        out[(size_t)st * B * D + (size_t)g * D + d] = A * __builtin_amdgcn_rcpf(Ls);
    }
}

// ---------------------------------------------------------------------------
extern "C" void kernel_launch(void* const* d_in, const int* in_sizes, int n_in,
                              void* d_out, int out_size, void* d_ws, size_t ws_size,
                              hipStream_t stream) {
    const float* xI    = (const float*)d_in[0];
    const float* xV    = (const float*)d_in[1];
    const float* Wu    = (const float*)d_in[2];
    const float* bu    = (const float*)d_in[3];
    const float* Wv    = (const float*)d_in[4];
    const float* We    = (const float*)d_in[5];
    // d_in[6] = seg_ids (unused: segments contiguous, last_nodes suffices)
    const int*   lastn = (const int*)d_in[7];
    const int B = in_sizes[7];               // 8192

    float*  vIb   = (float*)d_ws;
    float*  vVb   = vIb + (size_t)B * D;
    short8* fragW = (short8*)(vVb + (size_t)B * D);

    pack_wu<<<8, 256, 0, stream>>>(Wu, fragW);
    gate_k<<<B, 128, 0, stream>>>(xI, xV, Wv, bu, lastn, vIb, vVb);
    attn_main<<<B, 256, 0, stream>>>(xI, xV, We, lastn, vIb, vVb, fragW,
                                     (float*)d_out, B);
}

// Round 4
// 271.028 us; speedup vs baseline: 2.2028x; 1.5473x over previous
//
#include <hip/hip_runtime.h>
#include <stdint.h>

typedef short short8 __attribute__((ext_vector_type(8)));
typedef float f32x4 __attribute__((ext_vector_type(4)));

#define D 128
#define LOG2E 1.44269504088896340736f

__device__ __forceinline__ unsigned short f2bf(float f) {
    union { float f; unsigned u; } v; v.f = f;
    unsigned u = v.u;
    unsigned r = (u + 0x7FFFu + ((u >> 16) & 1u)) >> 16;  // RNE
    return (unsigned short)r;
}

// pack two f32 -> one u32 of two bf16 (round-half-up via +0x8000, then v_perm)
__device__ __forceinline__ unsigned packbf(float x, float y) {
    unsigned ux = __float_as_uint(x) + 0x8000u;
    unsigned uy = __float_as_uint(y) + 0x8000u;
    return __builtin_amdgcn_perm(uy, ux, 0x07060302u);
}

__device__ __forceinline__ float sigm2(float z) {   // sigmoid, z in log2 units
    return __builtin_amdgcn_rcpf(1.f + __builtin_amdgcn_exp2f(-z));
}

// HBM -> LDS direct (16B per lane). LDS dest must be linear base + lane*16.
__device__ __forceinline__ void gld16(const float* g, float* l) {
    __builtin_amdgcn_global_load_lds(
        (const __attribute__((address_space(1))) void*)g,
        (__attribute__((address_space(3))) void*)l, 16, 0, 0);
}

// ---------------------------------------------------------------------------
// Kernel 1: pre-pack (Wu * log2e) as bf16 MFMA B-fragments.
// t = nt*256 + kk*64 + lane holds B[k][col], col = nt*16+(lane&15),
// k = kk*32+(lane>>4)*8+j  (B[k][col] = Wu[col][k], u = f @ Wu^T)
// ---------------------------------------------------------------------------
__global__ __launch_bounds__(256) void pack_wu(const float* __restrict__ Wu,
                                               short8* __restrict__ frag) {
    int tid = blockIdx.x * 256 + threadIdx.x;
    int nt = tid >> 8, kk = (tid >> 6) & 3, l = tid & 63;
    int col = nt * 16 + (l & 15);
    int kb  = kk * 32 + ((l >> 4) * 8);
    short8 o;
#pragma unroll
    for (int j = 0; j < 8; ++j) o[j] = (short)f2bf(Wu[col * D + kb + j] * LOG2E);
    frag[tid] = o;
}

// ---------------------------------------------------------------------------
// Kernel 2: per-graph gates (log2e pre-scaled)
// ---------------------------------------------------------------------------
__global__ __launch_bounds__(128) void gate_k(const float* __restrict__ xI,
                                              const float* __restrict__ xV,
                                              const float* __restrict__ Wv,
                                              const float* __restrict__ bu,
                                              const int* __restrict__ lastn,
                                              float* __restrict__ vIb,
                                              float* __restrict__ vVb) {
    __shared__ float xi[D], xv[D];
    int g = blockIdx.x, t = threadIdx.x;
    int r = lastn[g];
    xi[t] = xI[(size_t)r * D + t];
    xv[t] = xV[(size_t)r * D + t];
    __syncthreads();
    const float4* wr = (const float4*)(Wv + (size_t)t * D);
    const float4* a4 = (const float4*)xi;
    const float4* b4 = (const float4*)xv;
    float sI = 0.f, sV = 0.f;
#pragma unroll 8
    for (int i = 0; i < D / 4; ++i) {
        float4 w = wr[i], a = a4[i], b = b4[i];
        sI += w.x * a.x + w.y * a.y + w.z * a.z + w.w * a.w;
        sV += w.x * b.x + w.y * b.y + w.z * b.z + w.w * b.w;
    }
    float bias = bu[t];
    vIb[(size_t)g * D + t] = (sI + bias) * LOG2E;
    vVb[(size_t)g * D + t] = (sV + bias) * LOG2E;
}

// ---------------------------------------------------------------------------
// Kernel 3: fused main. Block per graph, 4 waves striding 16-row chunks.
// HBM -> LDS via global_load_lds (no VGPR transit, no spills). Swizzle
// (unit ^= row&7, 16B units) applied by pre-swizzling the per-lane GLOBAL
// source; LDS dest stays linear. Read side identical to round 3 (verified).
// Pipeline: read chunk c from LDS into regs -> issue c+4 loads -> compute.
// ---------------------------------------------------------------------------
__global__ __launch_bounds__(256) void attn_main(
    const float* __restrict__ xI, const float* __restrict__ xV,
    const float* __restrict__ We, const int* __restrict__ lastn,
    const float* __restrict__ vIb, const float* __restrict__ vVb,
    const short8* __restrict__ fragG, float* __restrict__ out, int B) {
    __shared__ short8 bfrag[2048];                       // 32 KB Wu fragments
    __shared__ __align__(16) float rbuf[4][2048];        // 32 KB row chunks
    __shared__ float gl[3][D];                           // We*log2e, vI, vV
    __shared__ float cmbA[2][4][D];                      // combine
    __shared__ float cmbM[2][4], cmbL[2][4];

    int t = threadIdx.x, lane = t & 63, w = t >> 6;
    int g = blockIdx.x;

    {   // stage Wu fragments (contiguous 16B/lane)
        const uint4* srcf = (const uint4*)fragG;
        uint4* dst = (uint4*)bfrag;
#pragma unroll
        for (int i = 0; i < 8; ++i) dst[i * 256 + t] = srcf[i * 256 + t];
    }
    if (t < D) {
        gl[0][t] = We[t] * LOG2E;
        gl[1][t] = vIb[(size_t)g * D + t];
        gl[2][t] = vVb[(size_t)g * D + t];
    }

    int s = (g == 0) ? 0 : (lastn[g - 1] + 1);
    int n = lastn[g] + 1 - s;                     // >= 1

    int ch = (n + 15) >> 4;
    int total = 2 * ch;
    float* rb = &rbuf[w][0];

    // issue 8 global_load_lds for chunk cc into this wave's buffer.
    // LDS byte p = i*1024 + lane*16; row = p>>9; physical unit = lane&31;
    // logical unit = (lane&31) ^ (row&7)  (swizzle involution on source).
    auto issue = [&](int cc) {
        int hf = (cc >= ch) ? 1 : 0;
        const float* sp = hf ? xV : xI;
        int bb = (cc - hf * ch) << 4;
#pragma unroll
        for (int i = 0; i < 8; ++i) {
            int row = (i << 1) + (lane >> 5);
            int rr = bb + row; if (rr > n - 1) rr = n - 1;
            int lu = (lane & 31) ^ (row & 7);
            gld16(sp + (size_t)(s + rr) * D + (lu << 2),
                  rb + (i << 8) + (lane << 2));
        }
    };

    if (w < total) issue(w);
    __syncthreads();       // bfrag + gl visible to all waves

    float mI = -__builtin_inff(), mV = -__builtin_inff();
    float lIs = 0.f, lVs = 0.f;
    float aI0 = 0.f, aI1 = 0.f, aV0 = 0.f, aV1 = 0.f;

    for (int c = w; c < total; c += 4) {
        int hf = (c >= ch) ? 1 : 0;
        int base = (c - hf * ch) << 4;

        asm volatile("s_waitcnt vmcnt(0)" ::: "memory");   // chunk c landed
        __builtin_amdgcn_sched_barrier(0);

        // ---- A fragments from LDS: row = lane&15, dims (lane>>4)*8 + kk*32
        short8 af[4];
        int arow = lane & 15;
        int sw = (arow & 7) << 4;
        const char* rbc = (const char*)rb;
#pragma unroll
        for (int kk = 0; kk < 4; ++kk) {
            int byte = (arow << 9) + ((lane >> 4) << 5) + (kk << 7);
            float4 f0 = *(const float4*)(rbc + (byte ^ sw));
            float4 f1 = *(const float4*)(rbc + ((byte + 16) ^ sw));
            union { unsigned u[4]; short8 s8; } cv;
            cv.u[0] = packbf(f0.x, f0.y);
            cv.u[1] = packbf(f0.z, f0.w);
            cv.u[2] = packbf(f1.x, f1.y);
            cv.u[3] = packbf(f1.z, f1.w);
            af[kk] = cv.s8;
        }
        // ---- accumulate operands into regs (frees the LDS buffer) ----
        float fr0[16], fr1[16];
#pragma unroll
        for (int r = 0; r < 16; ++r) {
            int rsw = (r & 7) << 4;
            fr0[r] = *(const float*)(rbc + (((r << 9) + (lane << 2)) ^ rsw));
            fr1[r] = *(const float*)(rbc + (((r << 9) + 256 + (lane << 2)) ^ rsw));
        }
        asm volatile("s_waitcnt lgkmcnt(0)" ::: "memory"); // LDS reads done
        __builtin_amdgcn_sched_barrier(0);
        if (c + 4 < total) issue(c + 4);    // prefetch (hidden by compute)

        // ---- GEMM + gate epilogue (e in log2 units) ----
        float pI[4] = {0.f, 0.f, 0.f, 0.f}, pV[4] = {0.f, 0.f, 0.f, 0.f};
#pragma unroll
        for (int nt = 0; nt < 8; ++nt) {
            f32x4 dacc = {0.f, 0.f, 0.f, 0.f};
#pragma unroll
            for (int kk = 0; kk < 4; ++kk)
                dacc = __builtin_amdgcn_mfma_f32_16x16x32_bf16(
                    af[kk], bfrag[nt * 256 + kk * 64 + lane], dacc, 0, 0, 0);
            int col = nt * 16 + (lane & 15);
            float we = gl[0][col], vI = gl[1][col], vV = gl[2][col];
#pragma unroll
            for (int q = 0; q < 4; ++q) {
                float u = dacc[q];
                pI[q] = fmaf(we, sigm2(u + vI), pI[q]);
                pV[q] = fmaf(we, sigm2(u + vV), pV[q]);
            }
        }
        // reduce across 16 lanes (cols); mask invalid rows
#pragma unroll
        for (int q = 0; q < 4; ++q) {
#pragma unroll
            for (int off = 1; off < 16; off <<= 1) {
                pI[q] += __shfl_xor(pI[q], off);
                pV[q] += __shfl_xor(pV[q], off);
            }
            int r = ((lane >> 4) * 4) + q;
            if (base + r >= n) { pI[q] = -__builtin_inff(); pV[q] = -__builtin_inff(); }
        }
        float cmI = fmaxf(fmaxf(pI[0], pI[1]), fmaxf(pI[2], pI[3]));
        float cmV = fmaxf(fmaxf(pV[0], pV[1]), fmaxf(pV[2], pV[3]));
        cmI = fmaxf(cmI, __shfl_xor(cmI, 16)); cmI = fmaxf(cmI, __shfl_xor(cmI, 32));
        cmV = fmaxf(cmV, __shfl_xor(cmV, 16)); cmV = fmaxf(cmV, __shfl_xor(cmV, 32));

        float mnI = fmaxf(mI, cmI), mnV = fmaxf(mV, cmV);
        float scI = __builtin_amdgcn_exp2f(mI - mnI);
        float scV = __builtin_amdgcn_exp2f(mV - mnV);
        lIs *= scI; lVs *= scV;
        aI0 *= scI; aI1 *= scI; aV0 *= scV; aV1 *= scV;

        float wIq[4], wVq[4];
#pragma unroll
        for (int q = 0; q < 4; ++q) {
            wIq[q] = __builtin_amdgcn_exp2f(pI[q] - mnI);   // 0 for masked rows
            wVq[q] = __builtin_amdgcn_exp2f(pV[q] - mnV);
        }
        float sIq = wIq[0] + wIq[1] + wIq[2] + wIq[3];
        float sVq = wVq[0] + wVq[1] + wVq[2] + wVq[3];
        sIq += __shfl_xor(sIq, 16); sIq += __shfl_xor(sIq, 32);
        sVq += __shfl_xor(sVq, 16); sVq += __shfl_xor(sVq, 32);
        lIs += sIq; lVs += sVq;

        // weighted accumulate from registers
#pragma unroll
        for (int r = 0; r < 16; ++r) {
            float wI = __shfl(wIq[r & 3], (r >> 2) << 4);
            float wV = __shfl(wVq[r & 3], (r >> 2) << 4);
            aI0 = fmaf(wI, fr0[r], aI0); aI1 = fmaf(wI, fr1[r], aI1);
            aV0 = fmaf(wV, fr0[r], aV0); aV1 = fmaf(wV, fr1[r], aV1);
        }
        mI = mnI; mV = mnV;
    }

    // ---- cross-wave flash combine ----
    cmbA[0][w][lane] = aI0; cmbA[0][w][lane + 64] = aI1;
    cmbA[1][w][lane] = aV0; cmbA[1][w][lane + 64] = aV1;
    if (lane == 0) {
        cmbM[0][w] = mI; cmbL[0][w] = lIs;
        cmbM[1][w] = mV; cmbL[1][w] = lVs;
    }
    __syncthreads();
    {
        int st = t >> 7, d = t & 127;
        float M = fmaxf(fmaxf(cmbM[st][0], cmbM[st][1]),
                        fmaxf(cmbM[st][2], cmbM[st][3]));
        float Ls = 0.f, A = 0.f;
#pragma unroll
        for (int ww = 0; ww < 4; ++ww) {
            float e = __builtin_amdgcn_exp2f(cmbM[st][ww] - M);  // 0 for idle waves
            Ls += cmbL[st][ww] * e;
            A  += cmbA[st][ww][d] * e;
        }
        out[(size_t)st * B * D + (size_t)g * D + d] = A * __builtin_amdgcn_rcpf(Ls);
    }
}

// ---------------------------------------------------------------------------
extern "C" void kernel_launch(void* const* d_in, const int* in_sizes, int n_in,
                              void* d_out, int out_size, void* d_ws, size_t ws_size,
                              hipStream_t stream) {
    const float* xI    = (const float*)d_in[0];
    const float* xV    = (const float*)d_in[1];
    const float* Wu    = (const float*)d_in[2];
    const float* bu    = (const float*)d_in[3];
    const float* Wv    = (const float*)d_in[4];
    const float* We    = (const float*)d_in[5];
    // d_in[6] = seg_ids (unused: segments contiguous, last_nodes suffices)
    const int*   lastn = (const int*)d_in[7];
    const int B = in_sizes[7];               // 8192

    float*  vIb   = (float*)d_ws;
    float*  vVb   = vIb + (size_t)B * D;
    short8* fragW = (short8*)(vVb + (size_t)B * D);

    pack_wu<<<8, 256, 0, stream>>>(Wu, fragW);
    gate_k<<<B, 128, 0, stream>>>(xI, xV, Wv, bu, lastn, vIb, vVb);
    attn_main<<<B, 256, 0, stream>>>(xI, xV, We, lastn, vIb, vVb, fragW,
                                     (float*)d_out, B);
}